// Round 16
// baseline (182.542 us; speedup 1.0000x reference)
//
#include <hip/hip_runtime.h>
#include <hip/hip_bf16.h>

#define NB 4
#define CH 256
#define HH 64
#define WW 64
#define NPIX 4096      // HH*WW
#define OH 62
#define NPATCH 3844    // 62*62
#define KDIM 256       // == CH
#define EPSN 1e-12f
#define VROW 68        // V row stride (floats): 16B-aligned rows
#define SEG 8          // diagonal segment length (pairs per block) — small = more TLP

typedef __attribute__((ext_vector_type(8))) short short8;
typedef __attribute__((ext_vector_type(4))) float f32x4;

__device__ __forceinline__ float bf16_to_f32(unsigned short u) {
    return __uint_as_float((unsigned)u << 16);
}
__device__ __forceinline__ unsigned short f32_to_bf16(float f) {
    __hip_bfloat16 h = __float2bfloat16(f);
    return *(unsigned short*)&h;
}

// ---- K1 (fused prep): read inputs ONCE; per-pixel ss + inv-norm; normalized bf16
// ---- transpose (C,pix)->(pix,C). Also zero-inits d_out + keys.
__global__ __launch_bounds__(256) void k_prep(const float* __restrict__ pred,
                                              const float* __restrict__ tgt,
                                              __hip_bfloat16* __restrict__ Xn,
                                              __hip_bfloat16* __restrict__ Tn,
                                              float* __restrict__ ssP, float* __restrict__ invP,
                                              float* __restrict__ ssT, float* __restrict__ invT,
                                              unsigned long long* __restrict__ keys,
                                              float* __restrict__ out) {
    const int bz = blockIdx.y;            // 0..7
    const int b = bz >> 1, which = bz & 1;
    const float* src = (which ? tgt : pred) + (size_t)b * CH * NPIX;
    unsigned short* dst = (unsigned short*)((which ? Tn : Xn) + (size_t)b * NPIX * CH);
    float* ss_g  = (which ? ssT  : ssP)  + b * NPIX;
    float* inv_g = (which ? invT : invP) + b * NPIX;
    const int pix0 = blockIdx.x * 64;
    const int t = threadIdx.x, lane = t & 63, wv = t >> 6;

    int gid = (bz * 64 + blockIdx.x) * 256 + t;
    if (gid < NB * NPATCH) keys[gid] = 0ull;
    if (gid == 0) out[0] = 0.f;

    __shared__ unsigned short stage[CH][65];   // bf16, +1 pad
    __shared__ float partial[4][64];
    __shared__ float inv_s[64];

    float ssacc = 0.f;
#pragma unroll 8
    for (int cc = 0; cc < 64; ++cc) {
        int c = wv * 64 + cc;
        float v = src[(size_t)c * NPIX + pix0 + lane];
        ssacc += v * v;
        stage[c][lane] = f32_to_bf16(v);
    }
    partial[wv][lane] = ssacc;
    __syncthreads();
    if (t < 64) {
        float ss = partial[0][t] + partial[1][t] + partial[2][t] + partial[3][t];
        float inv = 1.f / fmaxf(sqrtf(ss), EPSN);
        ss_g[pix0 + t] = ss;
        inv_g[pix0 + t] = inv;
        inv_s[t] = inv;
    }
    __syncthreads();
    for (int p = wv; p < 64; p += 4) {
        float iv = inv_s[p];
#pragma unroll
        for (int cb = 0; cb < 4; ++cb) {
            int c = cb * 64 + lane;
            float v = bf16_to_f32(stage[c][p]) * iv;
            dst[(size_t)(pix0 + p) * CH + c] = f32_to_bf16(v);
        }
    }
}

// ------- K2: D = Xn * Tn^T (4096x4096, K=256, bf16 MFMA, bf16 OUTPUT), z = batch.
// 512 thr / 8 waves, 32x64 per wave. BK=32 double-buffer (32 KB LDS -> 4 blocks/CU)
// + CORRECTED swizzle: with 64B rows, bank group = (row*4 + slot) mod 8; slot must
// be xor'd with (row>>1)&3 (NOT row&3) so row-parity supplies group bit 2 and the
// xor supplies bits 0-1 -> 8 consecutive lanes hit all 8 groups = conflict-free.
// (R15's xor(row&3) covered only 4 groups -> same 6.3M conflicts as no swizzle.)
// D bit-identical: swizzle only permutes staging lanes.
__device__ __forceinline__ void gload_lds16(const void* g, void* l) {
    __builtin_amdgcn_global_load_lds(
        (const __attribute__((address_space(1))) void*)g,
        (__attribute__((address_space(3))) void*)l, 16, 0, 0);
}

__global__ __launch_bounds__(512) void k_gemm(const __hip_bfloat16* __restrict__ A,
                                              const __hip_bfloat16* __restrict__ Bm,
                                              unsigned short* __restrict__ Dout) {
    __shared__ short As[2][4096];   // [buf][row*32 + slot*8], 128 rows x BK=32
    __shared__ short Bs[2][4096];   // 32 KB total
    const int z = blockIdx.z;
    const int t = threadIdx.x;
    const int lane = t & 63, wv = t >> 6;          // 8 waves
    const int wm = wv >> 1, wn = wv & 1;           // 4x2 wave grid, 32x64 each
    const int row0 = blockIdx.y * 128, col0 = blockIdx.x * 128;
    const short* Ag = (const short*)A + (size_t)z * NPIX * CH;
    const short* Bg = (const short*)Bm + (size_t)z * NPIX * CH;
    unsigned short* D = Dout + (size_t)z * NPIX * NPIX;

    // staging: thread t covers row t>>2, LDS slot t&3; fetches global chunk
    // (t&3) ^ ((row>>1)&3). DMA dest = wave base + lane*16B (row*64B + slot*16B).
    const int srow = t >> 2;
    const int kce  = ((t & 3) ^ ((srow >> 1) & 3)) * 8;   // global elem offset in BK=32

    f32x4 acc[2][4] = {};

#define STAGE_K(buf, k0)                                                               \
    do {                                                                               \
        gload_lds16(Ag + (size_t)(row0 + srow) * KDIM + (k0) + kce, &As[buf][wv * 512]); \
        gload_lds16(Bg + (size_t)(col0 + srow) * KDIM + (k0) + kce, &Bs[buf][wv * 512]); \
    } while (0)

    STAGE_K(0, 0);

    const int rsel = lane & 15, kq = lane >> 4;
    // fragment row = 16*m + rsel (m = multiple of 16 base) -> (row>>1)&3 == (rsel>>1)&3
    const int pk = (kq ^ ((rsel >> 1) & 3)) * 8;   // swizzled slot offset (shorts)
#pragma unroll
    for (int it = 0; it < 8; ++it) {
        __syncthreads();                            // buf[it&1] ready
        const int buf = it & 1;
        if (it < 7) STAGE_K(buf ^ 1, (it + 1) * 32);
        short8 a[2], bfr[4];
#pragma unroll
        for (int mi = 0; mi < 2; ++mi)
            a[mi] = *(const short8*)&As[buf][(wm * 32 + mi * 16 + rsel) * 32 + pk];
#pragma unroll
        for (int ni = 0; ni < 4; ++ni)
            bfr[ni] = *(const short8*)&Bs[buf][(wn * 64 + ni * 16 + rsel) * 32 + pk];
#pragma unroll
        for (int mi = 0; mi < 2; ++mi)
#pragma unroll
            for (int ni = 0; ni < 4; ++ni)
                acc[mi][ni] = __builtin_amdgcn_mfma_f32_16x16x32_bf16(a[mi], bfr[ni], acc[mi][ni], 0, 0, 0);
    }
#undef STAGE_K
    const int rbase = (lane >> 4) * 4, cbase = lane & 15;
#pragma unroll
    for (int mi = 0; mi < 2; ++mi) {
#pragma unroll
        for (int ni = 0; ni < 4; ++ni) {
            int r0 = row0 + wm * 32 + mi * 16 + rbase;
            int c  = col0 + wn * 64 + ni * 16 + cbase;
#pragma unroll
            for (int r = 0; r < 4; ++r)
                D[(size_t)(r0 + r) * NPIX + c] = f32_to_bf16(acc[mi][ni][r]);
        }
    }
}

__device__ __forceinline__ void load_tile16(const unsigned short* __restrict__ D,
                                            int row, int col, float* f) {
    const unsigned short* rp = D + (size_t)row * NPIX + col;
    uint4 u0 = *(const uint4*)rp;
    uint4 u1 = *(const uint4*)(rp + 8);
    const unsigned* w0 = (const unsigned*)&u0;
    const unsigned* w1 = (const unsigned*)&u1;
#pragma unroll
    for (int w = 0; w < 4; ++w) {
        f[2 * w]         = bf16_to_f32((unsigned short)w0[w]);
        f[2 * w + 1]     = bf16_to_f32((unsigned short)(w0[w] >> 16));
        f[8 + 2 * w]     = bf16_to_f32((unsigned short)w1[w]);
        f[8 + 2 * w + 1] = bf16_to_f32((unsigned short)(w1[w] >> 16));
    }
}

// ---- K3 (k_score): rolling diagonal segments, SEG=8, TLP-first (R15-verified).
// ~3900 light blocks hide per-step LLC latency; V-sum order unchanged.
__global__ __launch_bounds__(256) void k_score(const unsigned short* __restrict__ Dbase,
                                               unsigned long long* __restrict__ keys) {
    const int z = blockIdx.z;
    const unsigned short* D = Dbase + (size_t)z * NPIX * NPIX;
    const int t = threadIdx.x;

    const int d = (int)blockIdx.x - 61;            // diagonal qr-pr in [-61, 61]
    const int adg = d < 0 ? -d : d;
    const int len = 62 - adg;
    const int s0 = blockIdx.y * SEG;
    if (s0 >= len) return;
    const int steps = min(SEG, len - s0);
    const int qr0 = (d > 0 ? d : 0) + s0;
    const int pr0 = qr0 - d;

    __shared__ __align__(16) float V[64 * VROW];   // 17408 B -> 9 blocks/CU

    const int a = t >> 2, b0 = (t & 3) * 16;
    const int g = t >> 6, qc = t & 63;
    const int qcr = qc < OH ? qc : (OH - 1);
    const int pc0 = g * 16;
    const int kmax = (g == 3) ? 14 : 16;

    float A[16], B[16], C[16];
    load_tile16(D, (qr0 + 0) * 64 + a, (pr0 + 0) * 64 + b0, A);
    load_tile16(D, (qr0 + 1) * 64 + a, (pr0 + 1) * 64 + b0, B);

    for (int k = 0; k < steps; ++k) {
        load_tile16(D, (qr0 + k + 2) * 64 + a, (pr0 + k + 2) * 64 + b0, C);
        float v[16];
#pragma unroll
        for (int e = 0; e < 16; ++e) v[e] = A[e] + B[e] + C[e];
        if (k) __syncthreads();                    // step k-1 score reads done
#pragma unroll
        for (int e = 0; e < 16; e += 4)
            *(f32x4*)&V[a * VROW + b0 + e] = *(const f32x4*)&v[e];
        __syncthreads();

        float r0[16], r1[20], r2[20];
#pragma unroll
        for (int e = 0; e < 16; e += 4)
            *(f32x4*)&r0[e] = *(const f32x4*)&V[qcr * VROW + pc0 + e];
#pragma unroll
        for (int e = 0; e < 20; e += 4)
            *(f32x4*)&r1[e] = *(const f32x4*)&V[(qcr + 1) * VROW + pc0 + e];
#pragma unroll
        for (int e = 0; e < 20; e += 4)
            *(f32x4*)&r2[e] = *(const f32x4*)&V[(qcr + 2) * VROW + pc0 + e];
        float best = -1e30f; int bpc = 0;
#pragma unroll
        for (int kk = 0; kk < 16; ++kk) {
            float s = r0[kk] + r1[kk + 1] + r2[kk + 2];
            if (kk < kmax && s > best) { best = s; bpc = pc0 + kk; }
        }
        if (qc < OH) {
            unsigned u = __float_as_uint(best);
            u = (best >= 0.f) ? (u | 0x80000000u) : ~u;
            unsigned long long key = ((unsigned long long)u << 12)
                                   | (unsigned)((63 - (pr0 + k)) << 6)
                                   | (unsigned)(63 - bpc);
            atomicMax(&keys[(size_t)z * NPATCH + (qr0 + k) * OH + qc], key);
        }
#pragma unroll
        for (int e = 0; e < 16; ++e) { A[e] = B[e]; B[e] = C[e]; }
    }
}

// -------- K4 (k_loss): decode keys -> match; loss via norm expansion --------
__global__ void k_loss(const unsigned short* __restrict__ Dbase,
                       const unsigned long long* __restrict__ keys,
                       const float* __restrict__ ssPb, const float* __restrict__ invPb,
                       const float* __restrict__ ssTb, const float* __restrict__ invTb,
                       float* __restrict__ out) {
    const int z = blockIdx.y;
    const unsigned short* D = Dbase + (size_t)z * NPIX * NPIX;
    const float* ssP  = ssPb  + z * NPIX;
    const float* invP = invPb + z * NPIX;
    const float* ssT  = ssTb  + z * NPIX;
    const float* invT = invTb + z * NPIX;
    int q = blockIdx.x * 256 + threadIdx.x;
    float acc = 0.f;
    if (q < NPATCH) {
        int qr = q / OH, qc = q - qr * OH;
        int qpix = qr * WW + qc;
        unsigned long long key = keys[(size_t)z * NPATCH + q];
        int mpr = 63 - (int)((key >> 6) & 63);
        int mpc = 63 - (int)(key & 63);
        int mpix = mpr * WW + mpc;
#pragma unroll
        for (int i = 0; i < 3; ++i)
#pragma unroll
            for (int j = 0; j < 3; ++j) {
                int off = i * WW + j;
                int y = qpix + off, x = mpix + off;
                float Dv = bf16_to_f32(D[(size_t)y * NPIX + x]);
                float nP = ssP[y] * invP[y];       // = ||p_y||
                float nT = ssT[x] * invT[x];
                acc += ssP[y] + ssT[x] - 2.f * Dv * nP * nT;
            }
    }
#pragma unroll
    for (int s = 32; s > 0; s >>= 1) acc += __shfl_down(acc, s, 64);
    if ((threadIdx.x & 63) == 0)
        atomicAdd(out, acc * (1.f / 35426304.f));  // / (4*3844*2304)
}

// ---------------------------------- launch ----------------------------------
extern "C" void kernel_launch(void* const* d_in, const int* in_sizes, int n_in,
                              void* d_out, int out_size, void* d_ws, size_t ws_size,
                              hipStream_t stream) {
    const float* pred = (const float*)d_in[0];
    const float* tgt  = (const float*)d_in[1];
    char* ws = (char*)d_ws;
    // ws layout (bytes), ws_size = 256 MiB:
    // D(bf16, 4 batches) 128MB | Xn 8MB | Tn 8MB | norms 4x64KB | keys 123KB
    unsigned short*     Dws  = (unsigned short*)(ws);
    __hip_bfloat16*     Xn   = (__hip_bfloat16*)(ws + 134217728);
    __hip_bfloat16*     Tn   = (__hip_bfloat16*)(ws + 142606336);
    float*              ssP  = (float*)(ws + 150994944);
    float*              invP = (float*)(ws + 151060480);
    float*              ssT  = (float*)(ws + 151126016);
    float*              invT = (float*)(ws + 151191552);
    unsigned long long* keys = (unsigned long long*)(ws + 151257088);

    k_prep<<<dim3(64, 8), 256, 0, stream>>>(pred, tgt, Xn, Tn, ssP, invP, ssT, invT,
                                            keys, (float*)d_out);
    k_gemm<<<dim3(32, 32, 4), 512, 0, stream>>>(Xn, Tn, Dws);
    k_score<<<dim3(123, 8, 4), 256, 0, stream>>>(Dws, keys);
    k_loss<<<dim3(16, 4), 256, 0, stream>>>(Dws, keys, ssP, invP, ssT, invT,
                                            (float*)d_out);
}

// Round 17
// 175.609 us; speedup vs baseline: 1.0395x; 1.0395x over previous
//
#include <hip/hip_runtime.h>
#include <hip/hip_bf16.h>

#define NB 4
#define CH 256
#define HH 64
#define WW 64
#define NPIX 4096      // HH*WW
#define OH 62
#define NPATCH 3844    // 62*62
#define KDIM 256       // == CH
#define EPSN 1e-12f
#define VROW 68        // V row stride (floats): 16B-aligned rows
#define SEG 8          // diagonal segment length (pairs per block)
#define PST 68         // k_prep stage row stride (shorts): 8B-aligned rows

typedef __attribute__((ext_vector_type(8))) short short8;
typedef __attribute__((ext_vector_type(4))) float f32x4;

__device__ __forceinline__ float bf16_to_f32(unsigned short u) {
    return __uint_as_float((unsigned)u << 16);
}
__device__ __forceinline__ unsigned short f32_to_bf16(float f) {
    __hip_bfloat16 h = __float2bfloat16(f);
    return *(unsigned short*)&h;
}

// ---- K1 (fused prep): read inputs ONCE; per-pixel ss + inv-norm; normalized bf16
// ---- transpose (C,pix)->(pix,C). Vectorized: float4 global loads (1KB/wave/instr),
// ---- ushort4 stage writes (stride 68 -> 8B-aligned; 4-way bank = 1.58x, cheap).
// ---- Write phase: scalar reads/stores are the only 2-way-free pattern (checked).
// ---- Also zero-inits d_out + keys.
__global__ __launch_bounds__(256) void k_prep(const float* __restrict__ pred,
                                              const float* __restrict__ tgt,
                                              __hip_bfloat16* __restrict__ Xn,
                                              __hip_bfloat16* __restrict__ Tn,
                                              float* __restrict__ ssP, float* __restrict__ invP,
                                              float* __restrict__ ssT, float* __restrict__ invT,
                                              unsigned long long* __restrict__ keys,
                                              float* __restrict__ out) {
    const int bz = blockIdx.y;            // 0..7
    const int b = bz >> 1, which = bz & 1;
    const float* src = (which ? tgt : pred) + (size_t)b * CH * NPIX;
    unsigned short* dst = (unsigned short*)((which ? Tn : Xn) + (size_t)b * NPIX * CH);
    float* ss_g  = (which ? ssT  : ssP)  + b * NPIX;
    float* inv_g = (which ? invT : invP) + b * NPIX;
    const int pix0 = blockIdx.x * 64;
    const int t = threadIdx.x, lane = t & 63, wv = t >> 6;

    int gid = (bz * 64 + blockIdx.x) * 256 + t;
    if (gid < NB * NPATCH) keys[gid] = 0ull;
    if (gid == 0) out[0] = 0.f;

    __shared__ unsigned short stage[CH][PST];  // 34816 B
    __shared__ float partial[16][68];          // 4352 B (+pad: 2-way reads)
    __shared__ float inv_s[64];

    // load: thread (cb = t>>4, ch = t&15) covers c = cb*16+r (r<16), pixels ch*4..+3
    const int cb = t >> 4, chk = t & 15;
    float ss0 = 0.f, ss1 = 0.f, ss2 = 0.f, ss3 = 0.f;
#pragma unroll
    for (int r = 0; r < 16; ++r) {
        int c = cb * 16 + r;
        float4 v = *(const float4*)&src[(size_t)c * NPIX + pix0 + chk * 4];
        ss0 += v.x * v.x; ss1 += v.y * v.y; ss2 += v.z * v.z; ss3 += v.w * v.w;
        ushort4 sv;
        sv.x = f32_to_bf16(v.x); sv.y = f32_to_bf16(v.y);
        sv.z = f32_to_bf16(v.z); sv.w = f32_to_bf16(v.w);
        *(ushort4*)&stage[c][chk * 4] = sv;
    }
    float4 pv; pv.x = ss0; pv.y = ss1; pv.z = ss2; pv.w = ss3;
    *(float4*)&partial[cb][chk * 4] = pv;
    __syncthreads();
    if (t < 64) {
        float ss = 0.f;
#pragma unroll
        for (int r = 0; r < 16; ++r) ss += partial[r][t];
        float inv = 1.f / fmaxf(sqrtf(ss), EPSN);
        ss_g[pix0 + t] = ss;
        inv_g[pix0 + t] = inv;
        inv_s[t] = inv;
    }
    __syncthreads();
    // write: pixel p (16/wave), lane = c within 64-chunk; 2-way-free LDS reads
    for (int p = wv; p < 64; p += 4) {
        float iv = inv_s[p];
#pragma unroll
        for (int cc = 0; cc < 4; ++cc) {
            int c = cc * 64 + lane;
            float v = bf16_to_f32(stage[c][p]) * iv;
            dst[(size_t)(pix0 + p) * CH + c] = f32_to_bf16(v);
        }
    }
}

// ------- K2: D = Xn * Tn^T (4096x4096, K=256, bf16 MFMA, bf16 OUTPUT), z = batch.
// R13 config (measured best, 54.5 us): 512 thr / 8 waves, 32x64 per wave, BK=64
// double-buffer (64 KB LDS, 2 blocks/CU — long prefetch flight beats occupancy
// for this shallow-K shape) + xor(r&7) swizzle (conflicts = 0, R13-measured).
__device__ __forceinline__ void gload_lds16(const void* g, void* l) {
    __builtin_amdgcn_global_load_lds(
        (const __attribute__((address_space(1))) void*)g,
        (__attribute__((address_space(3))) void*)l, 16, 0, 0);
}

__global__ __launch_bounds__(512) void k_gemm(const __hip_bfloat16* __restrict__ A,
                                              const __hip_bfloat16* __restrict__ Bm,
                                              unsigned short* __restrict__ Dout) {
    __shared__ short As[2][8192];   // [buf][row*64 + slot*8], row stride 128 B
    __shared__ short Bs[2][8192];   // 64 KB total
    const int z = blockIdx.z;
    const int t = threadIdx.x;
    const int lane = t & 63, wv = t >> 6;          // 8 waves
    const int wm = wv >> 1, wn = wv & 1;           // 4x2 wave grid, 32x64 each
    const int row0 = blockIdx.y * 128, col0 = blockIdx.x * 128;
    const short* Ag = (const short*)A + (size_t)z * NPIX * CH;
    const short* Bg = (const short*)Bm + (size_t)z * NPIX * CH;
    unsigned short* D = Dout + (size_t)z * NPIX * NPIX;

    const int srow = t >> 3;
    const int kce  = ((t & 7) ^ (srow & 7)) * 8;   // element offset within BK=64

    f32x4 acc[2][4] = {};

#define STAGE_K(buf, k0)                                                                  \
    do {                                                                                  \
        gload_lds16(Ag + (size_t)(row0 + srow) * KDIM + (k0) + kce,      &As[buf][wv * 512]);        \
        gload_lds16(Ag + (size_t)(row0 + 64 + srow) * KDIM + (k0) + kce, &As[buf][4096 + wv * 512]); \
        gload_lds16(Bg + (size_t)(col0 + srow) * KDIM + (k0) + kce,      &Bs[buf][wv * 512]);        \
        gload_lds16(Bg + (size_t)(col0 + 64 + srow) * KDIM + (k0) + kce, &Bs[buf][4096 + wv * 512]); \
    } while (0)

    STAGE_K(0, 0);

    const int rsel = lane & 15, kq = lane >> 4;
    const int rx = rsel & 7;
#pragma unroll
    for (int it = 0; it < 4; ++it) {
        __syncthreads();                            // buf[it&1] ready
        const int buf = it & 1;
        if (it < 3) STAGE_K(buf ^ 1, (it + 1) * 64);
#pragma unroll
        for (int s = 0; s < 2; ++s) {
            const int pk = (((s << 2) + kq) ^ rx) * 8;   // swizzled slot offset (shorts)
            short8 a[2], bfr[4];
#pragma unroll
            for (int mi = 0; mi < 2; ++mi)
                a[mi] = *(const short8*)&As[buf][(wm * 32 + mi * 16 + rsel) * 64 + pk];
#pragma unroll
            for (int ni = 0; ni < 4; ++ni)
                bfr[ni] = *(const short8*)&Bs[buf][(wn * 64 + ni * 16 + rsel) * 64 + pk];
#pragma unroll
            for (int mi = 0; mi < 2; ++mi)
#pragma unroll
                for (int ni = 0; ni < 4; ++ni)
                    acc[mi][ni] = __builtin_amdgcn_mfma_f32_16x16x32_bf16(a[mi], bfr[ni], acc[mi][ni], 0, 0, 0);
        }
    }
#undef STAGE_K
    // C/D layout: col = lane&15, row = (lane>>4)*4 + reg (scalar stores; L2 coalesces)
    const int rbase = (lane >> 4) * 4, cbase = lane & 15;
#pragma unroll
    for (int mi = 0; mi < 2; ++mi) {
#pragma unroll
        for (int ni = 0; ni < 4; ++ni) {
            int r0 = row0 + wm * 32 + mi * 16 + rbase;
            int c  = col0 + wn * 64 + ni * 16 + cbase;
#pragma unroll
            for (int r = 0; r < 4; ++r)
                D[(size_t)(r0 + r) * NPIX + c] = f32_to_bf16(acc[mi][ni][r]);
        }
    }
}

__device__ __forceinline__ void load_tile16(const unsigned short* __restrict__ D,
                                            int row, int col, float* f) {
    const unsigned short* rp = D + (size_t)row * NPIX + col;
    uint4 u0 = *(const uint4*)rp;
    uint4 u1 = *(const uint4*)(rp + 8);
    const unsigned* w0 = (const unsigned*)&u0;
    const unsigned* w1 = (const unsigned*)&u1;
#pragma unroll
    for (int w = 0; w < 4; ++w) {
        f[2 * w]         = bf16_to_f32((unsigned short)w0[w]);
        f[2 * w + 1]     = bf16_to_f32((unsigned short)(w0[w] >> 16));
        f[8 + 2 * w]     = bf16_to_f32((unsigned short)w1[w]);
        f[8 + 2 * w + 1] = bf16_to_f32((unsigned short)(w1[w] >> 16));
    }
}

// ---- K3 (k_score): rolling diagonal segments, SEG=8, TLP-first (R15-verified).
// ~3900 light blocks hide per-step LLC latency; V-sum order unchanged.
__global__ __launch_bounds__(256) void k_score(const unsigned short* __restrict__ Dbase,
                                               unsigned long long* __restrict__ keys) {
    const int z = blockIdx.z;
    const unsigned short* D = Dbase + (size_t)z * NPIX * NPIX;
    const int t = threadIdx.x;

    const int d = (int)blockIdx.x - 61;            // diagonal qr-pr in [-61, 61]
    const int adg = d < 0 ? -d : d;
    const int len = 62 - adg;
    const int s0 = blockIdx.y * SEG;
    if (s0 >= len) return;
    const int steps = min(SEG, len - s0);
    const int qr0 = (d > 0 ? d : 0) + s0;
    const int pr0 = qr0 - d;

    __shared__ __align__(16) float V[64 * VROW];   // 17408 B -> 9 blocks/CU

    const int a = t >> 2, b0 = (t & 3) * 16;
    const int g = t >> 6, qc = t & 63;
    const int qcr = qc < OH ? qc : (OH - 1);
    const int pc0 = g * 16;
    const int kmax = (g == 3) ? 14 : 16;

    float A[16], B[16], C[16];
    load_tile16(D, (qr0 + 0) * 64 + a, (pr0 + 0) * 64 + b0, A);
    load_tile16(D, (qr0 + 1) * 64 + a, (pr0 + 1) * 64 + b0, B);

    for (int k = 0; k < steps; ++k) {
        load_tile16(D, (qr0 + k + 2) * 64 + a, (pr0 + k + 2) * 64 + b0, C);
        float v[16];
#pragma unroll
        for (int e = 0; e < 16; ++e) v[e] = A[e] + B[e] + C[e];
        if (k) __syncthreads();                    // step k-1 score reads done
#pragma unroll
        for (int e = 0; e < 16; e += 4)
            *(f32x4*)&V[a * VROW + b0 + e] = *(const f32x4*)&v[e];
        __syncthreads();

        float r0[16], r1[20], r2[20];
#pragma unroll
        for (int e = 0; e < 16; e += 4)
            *(f32x4*)&r0[e] = *(const f32x4*)&V[qcr * VROW + pc0 + e];
#pragma unroll
        for (int e = 0; e < 20; e += 4)
            *(f32x4*)&r1[e] = *(const f32x4*)&V[(qcr + 1) * VROW + pc0 + e];
#pragma unroll
        for (int e = 0; e < 20; e += 4)
            *(f32x4*)&r2[e] = *(const f32x4*)&V[(qcr + 2) * VROW + pc0 + e];
        float best = -1e30f; int bpc = 0;
#pragma unroll
        for (int kk = 0; kk < 16; ++kk) {
            float s = r0[kk] + r1[kk + 1] + r2[kk + 2];
            if (kk < kmax && s > best) { best = s; bpc = pc0 + kk; }
        }
        if (qc < OH) {
            unsigned u = __float_as_uint(best);
            u = (best >= 0.f) ? (u | 0x80000000u) : ~u;
            unsigned long long key = ((unsigned long long)u << 12)
                                   | (unsigned)((63 - (pr0 + k)) << 6)
                                   | (unsigned)(63 - bpc);
            atomicMax(&keys[(size_t)z * NPATCH + (qr0 + k) * OH + qc], key);
        }
#pragma unroll
        for (int e = 0; e < 16; ++e) { A[e] = B[e]; B[e] = C[e]; }
    }
}

// -------- K4 (k_loss): decode keys -> match; loss via norm expansion --------
__global__ void k_loss(const unsigned short* __restrict__ Dbase,
                       const unsigned long long* __restrict__ keys,
                       const float* __restrict__ ssPb, const float* __restrict__ invPb,
                       const float* __restrict__ ssTb, const float* __restrict__ invTb,
                       float* __restrict__ out) {
    const int z = blockIdx.y;
    const unsigned short* D = Dbase + (size_t)z * NPIX * NPIX;
    const float* ssP  = ssPb  + z * NPIX;
    const float* invP = invPb + z * NPIX;
    const float* ssT  = ssTb  + z * NPIX;
    const float* invT = invTb + z * NPIX;
    int q = blockIdx.x * 256 + threadIdx.x;
    float acc = 0.f;
    if (q < NPATCH) {
        int qr = q / OH, qc = q - qr * OH;
        int qpix = qr * WW + qc;
        unsigned long long key = keys[(size_t)z * NPATCH + q];
        int mpr = 63 - (int)((key >> 6) & 63);
        int mpc = 63 - (int)(key & 63);
        int mpix = mpr * WW + mpc;
#pragma unroll
        for (int i = 0; i < 3; ++i)
#pragma unroll
            for (int j = 0; j < 3; ++j) {
                int off = i * WW + j;
                int y = qpix + off, x = mpix + off;
                float Dv = bf16_to_f32(D[(size_t)y * NPIX + x]);
                float nP = ssP[y] * invP[y];       // = ||p_y||
                float nT = ssT[x] * invT[x];
                acc += ssP[y] + ssT[x] - 2.f * Dv * nP * nT;
            }
    }
#pragma unroll
    for (int s = 32; s > 0; s >>= 1) acc += __shfl_down(acc, s, 64);
    if ((threadIdx.x & 63) == 0)
        atomicAdd(out, acc * (1.f / 35426304.f));  // / (4*3844*2304)
}

// ---------------------------------- launch ----------------------------------
extern "C" void kernel_launch(void* const* d_in, const int* in_sizes, int n_in,
                              void* d_out, int out_size, void* d_ws, size_t ws_size,
                              hipStream_t stream) {
    const float* pred = (const float*)d_in[0];
    const float* tgt  = (const float*)d_in[1];
    char* ws = (char*)d_ws;
    // ws layout (bytes), ws_size = 256 MiB:
    // D(bf16, 4 batches) 128MB | Xn 8MB | Tn 8MB | norms 4x64KB | keys 123KB
    unsigned short*     Dws  = (unsigned short*)(ws);
    __hip_bfloat16*     Xn   = (__hip_bfloat16*)(ws + 134217728);
    __hip_bfloat16*     Tn   = (__hip_bfloat16*)(ws + 142606336);
    float*              ssP  = (float*)(ws + 150994944);
    float*              invP = (float*)(ws + 151060480);
    float*              ssT  = (float*)(ws + 151126016);
    float*              invT = (float*)(ws + 151191552);
    unsigned long long* keys = (unsigned long long*)(ws + 151257088);

    k_prep<<<dim3(64, 8), 256, 0, stream>>>(pred, tgt, Xn, Tn, ssP, invP, ssT, invT,
                                            keys, (float*)d_out);
    k_gemm<<<dim3(32, 32, 4), 512, 0, stream>>>(Xn, Tn, Dws);
    k_score<<<dim3(123, 8, 4), 256, 0, stream>>>(Dws, keys);
    k_loss<<<dim3(16, 4), 256, 0, stream>>>(Dws, keys, ssP, invP, ssT, invT,
                                            (float*)d_out);
}